// Round 2
// baseline (7669.485 us; speedup 1.0000x reference)
//
#include <hip/hip_runtime.h>
#include <hip/hip_bf16.h>
#include <hip/hip_cooperative_groups.h>

namespace cg = cooperative_groups;

// ESN: h_m = tanh(W_res h_{m-1} + W_in x_{m-1} + b_in), readout on all states.
// Split-bf16 (hi/lo) MFMA everywhere precision matters. Recurrence runs as ONE
// persistent cooperative kernel: W_res slice stationary in LDS (swizzled),
// one grid.sync per step.

#define B_   64
#define T_   256
#define DIN  512
#define DRES 2048
#define DOUT 512

typedef __attribute__((ext_vector_type(8))) short short8;
typedef __attribute__((ext_vector_type(4))) float f32x4;

__device__ __forceinline__ unsigned short f2bf(float x) {
    unsigned int u = __float_as_uint(x);
    unsigned int r = u + 0x7fffu + ((u >> 16) & 1u);
    return (unsigned short)(r >> 16);
}
__device__ __forceinline__ float bf2f(unsigned short h) {
    return __uint_as_float(((unsigned int)h) << 16);
}

// ---------------- split f32 -> bf16 hi/lo ----------------
__global__ void split4_kern(const float4* __restrict__ src,
                            ushort4* __restrict__ hi, ushort4* __restrict__ lo, int n4) {
    int i = blockIdx.x * blockDim.x + threadIdx.x;
    int st = gridDim.x * blockDim.x;
    for (; i < n4; i += st) {
        float4 v = src[i];
        ushort4 h, l;
        h.x = f2bf(v.x); l.x = f2bf(v.x - bf2f(h.x));
        h.y = f2bf(v.y); l.y = f2bf(v.y - bf2f(h.y));
        h.z = f2bf(v.z); l.z = f2bf(v.z - bf2f(h.z));
        h.w = f2bf(v.w); l.w = f2bf(v.w - bf2f(h.w));
        hi[i] = h; lo[i] = l;
    }
}

// ---------------- u GEMM: states[m] = x_in[:,m-1,:] @ W_in^T + b_in ----------------
__global__ __launch_bounds__(256) void u_gemm(
    const unsigned short* __restrict__ x_hi, const unsigned short* __restrict__ x_lo,
    const unsigned short* __restrict__ Win_hi, const unsigned short* __restrict__ Win_lo,
    const float* __restrict__ b_in,
    unsigned short* __restrict__ st_hi, unsigned short* __restrict__ st_lo) {
    const int t = blockIdx.y;            // 0..254 -> m = t+1
    const int r0 = blockIdx.x * 64;
    const int tid = threadIdx.x;
    const int w = tid >> 6, l = tid & 63;
    const int lm = l & 15, lg = l >> 4;

    __shared__ __align__(16) unsigned short Bs[2][64][72];

    f32x4 acc[4][3];
#pragma unroll
    for (int nt = 0; nt < 4; ++nt)
#pragma unroll
        for (int q = 0; q < 3; ++q) acc[nt][q] = (f32x4)0.0f;

    const int ab = w * 16 + lm;
    const long xbase = ((long)ab * T_ + t) * DIN;

    for (int s = 0; s < 8; ++s) {
#pragma unroll
        for (int q = 0; q < 4; ++q) {
            int idx = q * 256 + tid;
            int mt = idx >> 9;
            int rem = idx & 511;
            int row = rem >> 3, k8 = rem & 7;
            const unsigned short* sp =
                (mt ? Win_lo : Win_hi) + (long)(r0 + row) * DIN + s * 64 + k8 * 8;
            *(short8*)&Bs[mt][row][k8 * 8] = *(const short8*)sp;
        }
        __syncthreads();
#pragma unroll
        for (int ki = 0; ki < 2; ++ki) {
            int k = s * 64 + ki * 32 + lg * 8;
            short8 ahi = *(const short8*)&x_hi[xbase + k];
            short8 alo = *(const short8*)&x_lo[xbase + k];
#pragma unroll
            for (int nt = 0; nt < 4; ++nt) {
                short8 bhi = *(const short8*)&Bs[0][nt * 16 + lm][ki * 32 + lg * 8];
                short8 blo = *(const short8*)&Bs[1][nt * 16 + lm][ki * 32 + lg * 8];
                acc[nt][0] = __builtin_amdgcn_mfma_f32_16x16x32_bf16(ahi, bhi, acc[nt][0], 0, 0, 0);
                acc[nt][1] = __builtin_amdgcn_mfma_f32_16x16x32_bf16(ahi, blo, acc[nt][1], 0, 0, 0);
                acc[nt][2] = __builtin_amdgcn_mfma_f32_16x16x32_bf16(alo, bhi, acc[nt][2], 0, 0, 0);
            }
        }
        __syncthreads();
    }
    const int m = t + 1;
#pragma unroll
    for (int nt = 0; nt < 4; ++nt) {
        f32x4 s4 = acc[nt][0] + acc[nt][1] + acc[nt][2];
        int r = r0 + nt * 16 + lm;
        float bias = b_in[r];
#pragma unroll
        for (int j = 0; j < 4; ++j) {
            int bb = w * 16 + lg * 4 + j;
            float v = s4[j] + bias;
            unsigned short h = f2bf(v);
            long o = ((long)m * B_ + bb) * DRES + r;
            st_hi[o] = h;
            st_lo[o] = f2bf(v - bf2f(h));
        }
    }
}

// ---------------- persistent recurrence: all 255 steps in one kernel ----------------
// 128 WGs x 1024 threads. WG owns rows r0..r0+15, full K. W hi/lo in LDS
// (swizzled). Waves: bh (b-half, 32 rows of A) x ks (K slice of 256).
__global__ __launch_bounds__(1024) void recur_persist(
    const unsigned short* __restrict__ W_hi, const unsigned short* __restrict__ W_lo,
    unsigned short* __restrict__ st_hi, unsigned short* __restrict__ st_lo) {
    extern __shared__ char smem[];                  // [0,131072): W hi|lo, [131072,...): red
    float* red = (float*)(smem + 131072);           // [2][7][32][18] f32
    const int r0 = blockIdx.x * 16;
    const int tid = threadIdx.x;
    const int w = tid >> 6, l = tid & 63;
    const int lm = l & 15, lg = l >> 4;
    const int ks = w & 7, bh = w >> 3;
    const int bbase = bh * 32;
    const size_t SL = (size_t)B_ * DRES;
    cg::grid_group grid = cg::this_grid();

    // stage W slice once: [2][16 rows][2048 k] bf16, 16B-chunk XOR swizzle
    for (int c = tid; c < 8192; c += 1024) {
        int mat = c >> 12;
        int row = (c >> 8) & 15;
        int k8  = c & 255;
        const unsigned short* src = (mat ? W_lo : W_hi) + (size_t)(r0 + row) * DRES + k8 * 8;
        int off = mat * 65536 + row * 4096 + ((k8 * 16) ^ ((row & 7) << 4));
        *(short8*)(smem + off) = *(const short8*)src;
    }
    __syncthreads();

    const int swz = (lm & 7) << 4;
    const char* Wrow_hi = smem + lm * 4096;
    const char* Wrow_lo = smem + 65536 + lm * 4096;

    for (int m = 1; m < T_; ++m) {
        if (m > 1) grid.sync();
        const unsigned short* hp_hi = st_hi + (size_t)(m - 1) * SL;
        const unsigned short* hp_lo = st_lo + (size_t)(m - 1) * SL;
        f32x4 acc[2][3];
#pragma unroll
        for (int bt = 0; bt < 2; ++bt)
#pragma unroll
            for (int q = 0; q < 3; ++q) acc[bt][q] = (f32x4)0.f;

#pragma unroll
        for (int j = 0; j < 8; ++j) {
            int kk = ks * 256 + j * 32;
            int kb = kk * 2 + lg * 16;
            short8 bhi = *(const short8*)(Wrow_hi + ((kb ^ swz)));
            short8 blo = *(const short8*)(Wrow_lo + ((kb ^ swz)));
#pragma unroll
            for (int bt = 0; bt < 2; ++bt) {
                size_t abase = (size_t)(bbase + bt * 16 + lm) * DRES + kk + lg * 8;
                short8 ahi = *(const short8*)(hp_hi + abase);
                short8 alo = *(const short8*)(hp_lo + abase);
                acc[bt][0] = __builtin_amdgcn_mfma_f32_16x16x32_bf16(ahi, bhi, acc[bt][0], 0, 0, 0);
                acc[bt][1] = __builtin_amdgcn_mfma_f32_16x16x32_bf16(ahi, blo, acc[bt][1], 0, 0, 0);
                acc[bt][2] = __builtin_amdgcn_mfma_f32_16x16x32_bf16(alo, bhi, acc[bt][2], 0, 0, 0);
            }
        }
        if (ks > 0) {
#pragma unroll
            for (int bt = 0; bt < 2; ++bt) {
                f32x4 s = acc[bt][0] + acc[bt][1] + acc[bt][2];
#pragma unroll
                for (int jj = 0; jj < 4; ++jj)
                    red[(bh * 7 + ks - 1) * 576 + (bt * 16 + lg * 4 + jj) * 18 + lm] = s[jj];
            }
        }
        __syncthreads();
        if (ks == 0) {
            unsigned short* hc_hi = st_hi + (size_t)m * SL;
            unsigned short* hc_lo = st_lo + (size_t)m * SL;
#pragma unroll
            for (int bt = 0; bt < 2; ++bt) {
                f32x4 s = acc[bt][0] + acc[bt][1] + acc[bt][2];
#pragma unroll
                for (int jj = 0; jj < 4; ++jj) {
                    int bl = bt * 16 + lg * 4 + jj;
                    float pre = s[jj];
#pragma unroll
                    for (int t = 0; t < 7; ++t)
                        pre += red[(bh * 7 + t) * 576 + bl * 18 + lm];
                    size_t o = (size_t)(bbase + bl) * DRES + r0 + lm;
                    pre += bf2f(hc_hi[o]) + bf2f(hc_lo[o]);   // u_m stored here
                    float h = tanhf(pre);
                    unsigned short hh = f2bf(h);
                    hc_hi[o] = hh;
                    hc_lo[o] = f2bf(h - bf2f(hh));
                }
            }
        }
    }
}

// ---------------- readout: out[b][t][o] = states[t][b][:] . W_out[o][:] + b_out ----------------
__global__ __launch_bounds__(256) void readout_kern(
    const unsigned short* __restrict__ st_hi,
    const unsigned short* __restrict__ Wout_hi,
    const float* __restrict__ b_out, float* __restrict__ out) {
    const int n0 = blockIdx.x * 128;
    const int row0 = blockIdx.y * 64;
    const int tid = threadIdx.x;
    const int w = tid >> 6, l = tid & 63;
    const int lm = l & 15, lg = l >> 4;

    __shared__ __align__(16) unsigned short Bs[128][72];

    f32x4 acc[8];
#pragma unroll
    for (int nt = 0; nt < 8; ++nt) acc[nt] = (f32x4)0.f;

    const int row = row0 + w * 16 + lm;
    const long abase = (long)row * DRES;

    for (int s = 0; s < 32; ++s) {
#pragma unroll
        for (int q = 0; q < 4; ++q) {
            int idx = q * 256 + tid;
            int r_ = idx >> 3, k8 = idx & 7;
            *(short8*)&Bs[r_][k8 * 8] =
                *(const short8*)(Wout_hi + (long)(n0 + r_) * DRES + s * 64 + k8 * 8);
        }
        __syncthreads();
#pragma unroll
        for (int ki = 0; ki < 2; ++ki) {
            short8 a = *(const short8*)&st_hi[abase + s * 64 + ki * 32 + lg * 8];
#pragma unroll
            for (int nt = 0; nt < 8; ++nt) {
                short8 bf = *(const short8*)&Bs[nt * 16 + lm][ki * 32 + lg * 8];
                acc[nt] = __builtin_amdgcn_mfma_f32_16x16x32_bf16(a, bf, acc[nt], 0, 0, 0);
            }
        }
        __syncthreads();
    }
#pragma unroll
    for (int nt = 0; nt < 8; ++nt) {
        int o = n0 + nt * 16 + lm;
        float bias = b_out[o];
#pragma unroll
        for (int j = 0; j < 4; ++j) {
            int rr = row0 + w * 16 + lg * 4 + j;
            int t = rr >> 6, bb = rr & 63;
            out[((long)bb * T_ + t) * DOUT + o] = acc[nt][j] + bias;
        }
    }
}

extern "C" void kernel_launch(void* const* d_in, const int* in_sizes, int n_in,
                              void* d_out, int out_size, void* d_ws, size_t ws_size,
                              hipStream_t stream) {
    const float* x_res_init = (const float*)d_in[0];
    const float* x_in       = (const float*)d_in[1];
    const float* W_in       = (const float*)d_in[2];
    const float* b_in       = (const float*)d_in[3];
    const float* W_res      = (const float*)d_in[4];
    const float* W_out      = (const float*)d_in[5];
    const float* b_out      = (const float*)d_in[6];
    float* out = (float*)d_out;

    char* p = (char*)d_ws;
    auto alloc = [&](size_t bytes) -> char* {
        char* r = p;
        p += (bytes + 255) & ~(size_t)255;
        return r;
    };
    const size_t SL = (size_t)B_ * DRES;
    unsigned short* st_hi   = (unsigned short*)alloc((size_t)T_ * SL * 2);
    unsigned short* st_lo   = (unsigned short*)alloc((size_t)T_ * SL * 2);
    unsigned short* Wres_hi = (unsigned short*)alloc((size_t)DRES * DRES * 2);
    unsigned short* Wres_lo = (unsigned short*)alloc((size_t)DRES * DRES * 2);
    unsigned short* Win_hi  = (unsigned short*)alloc((size_t)DRES * DIN * 2);
    unsigned short* Win_lo  = (unsigned short*)alloc((size_t)DRES * DIN * 2);
    unsigned short* Wout_hi = (unsigned short*)alloc((size_t)DOUT * DRES * 2);
    unsigned short* Wout_lo = (unsigned short*)alloc((size_t)DOUT * DRES * 2);
    unsigned short* x_hi    = (unsigned short*)alloc((size_t)B_ * T_ * DIN * 2);
    unsigned short* x_lo    = (unsigned short*)alloc((size_t)B_ * T_ * DIN * 2);

    auto launch_split = [&](const float* src, unsigned short* hi, unsigned short* lo, size_t n) {
        int n4 = (int)(n / 4);
        int blocks = (n4 + 255) / 256;
        if (blocks > 2048) blocks = 2048;
        split4_kern<<<blocks, 256, 0, stream>>>((const float4*)src, (ushort4*)hi, (ushort4*)lo, n4);
    };
    launch_split(W_res, Wres_hi, Wres_lo, (size_t)DRES * DRES);
    launch_split(W_in,  Win_hi,  Win_lo,  (size_t)DRES * DIN);
    launch_split(W_out, Wout_hi, Wout_lo, (size_t)DOUT * DRES);
    launch_split(x_in,  x_hi,    x_lo,    (size_t)B_ * T_ * DIN);
    launch_split(x_res_init, st_hi, st_lo, SL);  // states[0]

    // u into states[1..255]
    u_gemm<<<dim3(32, T_ - 1), 256, 0, stream>>>(x_hi, x_lo, Win_hi, Win_lo, b_in, st_hi, st_lo);

    // persistent recurrence (cooperative): 128 WGs x 1024 threads, 163328 B LDS
    const size_t shmem = 131072 + 2 * 7 * 32 * 18 * sizeof(float);  // 163328
    hipFuncSetAttribute(reinterpret_cast<const void*>(recur_persist),
                        hipFuncAttributeMaxDynamicSharedMemorySize, (int)shmem);
    void* kargs[] = { (void*)&Wres_hi, (void*)&Wres_lo, (void*)&st_hi, (void*)&st_lo };
    hipLaunchCooperativeKernel((const void*)recur_persist, dim3(128), dim3(1024),
                               kargs, (unsigned int)shmem, stream);

    // readout
    readout_kern<<<dim3(4, 256), 256, 0, stream>>>(st_hi, Wout_hi, b_out, out);
}

// Round 4
// 5681.802 us; speedup vs baseline: 1.3498x; 1.3498x over previous
//
#include <hip/hip_runtime.h>
#include <hip/hip_bf16.h>

// ESN: h_m = tanh(W_res h_{m-1} + W_in x_{m-1} + b_in), readout on all states.
// Recurrence: ONE persistent cooperative kernel, 64 WGs x 512 threads.
// W_res as two signed-i8 digit planes (scale 2^16) stationary in LDS (128KiB,
// swizzled); h as two i8 digit planes (scale 2^14) double-buffered in global.
// mfma_i32_16x16x64_i8 with all 4 digit products -> exact integer GEMM over
// quantized values. Custom sense-reversing grid barrier (64 arrivals).

#define B_   64
#define T_   256
#define DIN  512
#define DRES 2048
#define DOUT 512
#define NWG  64
#define SLQ  131072   // one h digit-plane slice: 64*2048 bytes

typedef __attribute__((ext_vector_type(8))) short short8;
typedef __attribute__((ext_vector_type(4))) float f32x4;
typedef __attribute__((ext_vector_type(4))) int i32x4;

__device__ __forceinline__ unsigned short f2bf(float x) {
    unsigned int u = __float_as_uint(x);
    unsigned int r = u + 0x7fffu + ((u >> 16) & 1u);
    return (unsigned short)(r >> 16);
}
__device__ __forceinline__ float bf2f(unsigned short h) {
    return __uint_as_float(((unsigned int)h) << 16);
}

// ---------------- split f32 -> bf16 hi/lo ----------------
__global__ void split4_kern(const float4* __restrict__ src,
                            ushort4* __restrict__ hi, ushort4* __restrict__ lo, int n4) {
    int i = blockIdx.x * blockDim.x + threadIdx.x;
    int st = gridDim.x * blockDim.x;
    for (; i < n4; i += st) {
        float4 v = src[i];
        ushort4 h, l;
        h.x = f2bf(v.x); l.x = f2bf(v.x - bf2f(h.x));
        h.y = f2bf(v.y); l.y = f2bf(v.y - bf2f(h.y));
        h.z = f2bf(v.z); l.z = f2bf(v.z - bf2f(h.z));
        h.w = f2bf(v.w); l.w = f2bf(v.w - bf2f(h.w));
        hi[i] = h; lo[i] = l;
    }
}

// ---------------- quantize f32 -> two signed-i8 digit planes ----------------
__global__ void quant_kern(const float* __restrict__ src, float scale,
                           char* __restrict__ d1, char* __restrict__ d0, int n) {
    int i = blockIdx.x * blockDim.x + threadIdx.x;
    int st = gridDim.x * blockDim.x;
    for (; i < n; i += st) {
        int q = (int)rintf(src[i] * scale);
        q = min(max(q, -32640), 32639);
        int h1 = (q + 128) >> 8;
        d1[i] = (char)h1;
        d0[i] = (char)(q - (h1 << 8));
    }
}

// ---------------- u GEMM: states[m] = x_in[:,m-1,:] @ W_in^T + b_in ----------------
__global__ __launch_bounds__(256) void u_gemm(
    const unsigned short* __restrict__ x_hi, const unsigned short* __restrict__ x_lo,
    const unsigned short* __restrict__ Win_hi, const unsigned short* __restrict__ Win_lo,
    const float* __restrict__ b_in,
    unsigned short* __restrict__ st_hi, unsigned short* __restrict__ st_lo) {
    const int t = blockIdx.y;            // 0..254 -> m = t+1
    const int r0 = blockIdx.x * 64;
    const int tid = threadIdx.x;
    const int w = tid >> 6, l = tid & 63;
    const int lm = l & 15, lg = l >> 4;

    __shared__ __align__(16) unsigned short Bs[2][64][72];

    f32x4 acc[4][3];
#pragma unroll
    for (int nt = 0; nt < 4; ++nt)
#pragma unroll
        for (int q = 0; q < 3; ++q) acc[nt][q] = (f32x4)0.0f;

    const int ab = w * 16 + lm;
    const long xbase = ((long)ab * T_ + t) * DIN;

    for (int s = 0; s < 8; ++s) {
#pragma unroll
        for (int q = 0; q < 4; ++q) {
            int idx = q * 256 + tid;
            int mt = idx >> 9;
            int rem = idx & 511;
            int row = rem >> 3, k8 = rem & 7;
            const unsigned short* sp =
                (mt ? Win_lo : Win_hi) + (long)(r0 + row) * DIN + s * 64 + k8 * 8;
            *(short8*)&Bs[mt][row][k8 * 8] = *(const short8*)sp;
        }
        __syncthreads();
#pragma unroll
        for (int ki = 0; ki < 2; ++ki) {
            int k = s * 64 + ki * 32 + lg * 8;
            short8 ahi = *(const short8*)&x_hi[xbase + k];
            short8 alo = *(const short8*)&x_lo[xbase + k];
#pragma unroll
            for (int nt = 0; nt < 4; ++nt) {
                short8 bhi = *(const short8*)&Bs[0][nt * 16 + lm][ki * 32 + lg * 8];
                short8 blo = *(const short8*)&Bs[1][nt * 16 + lm][ki * 32 + lg * 8];
                acc[nt][0] = __builtin_amdgcn_mfma_f32_16x16x32_bf16(ahi, bhi, acc[nt][0], 0, 0, 0);
                acc[nt][1] = __builtin_amdgcn_mfma_f32_16x16x32_bf16(ahi, blo, acc[nt][1], 0, 0, 0);
                acc[nt][2] = __builtin_amdgcn_mfma_f32_16x16x32_bf16(alo, bhi, acc[nt][2], 0, 0, 0);
            }
        }
        __syncthreads();
    }
    const int m = t + 1;
#pragma unroll
    for (int nt = 0; nt < 4; ++nt) {
        f32x4 s4 = acc[nt][0] + acc[nt][1] + acc[nt][2];
        int r = r0 + nt * 16 + lm;
        float bias = b_in[r];
#pragma unroll
        for (int j = 0; j < 4; ++j) {
            int bb = w * 16 + lg * 4 + j;
            float v = s4[j] + bias;
            unsigned short h = f2bf(v);
            long o = ((long)m * B_ + bb) * DRES + r;
            st_hi[o] = h;
            st_lo[o] = f2bf(v - bf2f(h));
        }
    }
}

// ---------------- persistent recurrence ----------------
// 64 WGs x 512 threads (8 waves). WG owns rows gr0..gr0+31, full K=2048.
// W digit planes in LDS (128 KiB, swizzled). Wave w: rt = w>>2 (row half),
// bt = w&3 (batch quarter); each wave computes a full-K 16x16 tile alone.
__global__ __launch_bounds__(512) void recur_persist(
    const char* __restrict__ wq1, const char* __restrict__ wq0,
    char* __restrict__ hq1, char* __restrict__ hq0,
    unsigned short* __restrict__ st_hi, const unsigned short* __restrict__ st_lo,
    unsigned* __restrict__ bar) {
    extern __shared__ char smem[];               // [0,64K): W1, [64K,128K): W0
    const int gr0 = blockIdx.x * 32;
    const int tid = threadIdx.x;
    const int w = tid >> 6, l = tid & 63;
    const int lm = l & 15, lg = l >> 4;
    const int rt = w >> 2, bt = w & 3;
    const int rloc = rt * 16 + lm;
    const int swz = (rloc & 7) << 4;
    const size_t SL = (size_t)B_ * DRES;

    // stage W digit planes once (swizzled 16B chunks)
    for (int c = tid; c < 8192; c += 512) {
        int mat = c >> 12;
        int rem = c & 4095;
        int row = rem >> 7, k16 = rem & 127;
        const char* src = (mat ? wq0 : wq1) + (size_t)(gr0 + row) * DRES + k16 * 16;
        int dst = mat * 65536 + row * 2048 + ((k16 * 16) ^ ((row & 7) << 4));
        *(i32x4*)(smem + dst) = *(const i32x4*)src;
    }
    __syncthreads();

    const char* lw1 = smem + rloc * 2048;
    const char* lw0 = smem + 65536 + rloc * 2048;
    unsigned* cnt = bar;
    unsigned* gen = bar + 32;

    for (int m = 1; m < T_; ++m) {
        const char* A1 = hq1 + (size_t)((m - 1) & 1) * SLQ;
        const char* A0 = hq0 + (size_t)((m - 1) & 1) * SLQ;
        // u preload (consumed in epilogue; L3 latency hides under MFMA phase)
        float us[4];
        {
            size_t sb = (size_t)m * SL + gr0 + rloc;
#pragma unroll
            for (int j = 0; j < 4; ++j) {
                size_t o = sb + (size_t)(bt * 16 + lg * 4 + j) * DRES;
                us[j] = bf2f(st_hi[o]) + bf2f(st_lo[o]);
            }
        }
        i32x4 a11 = (i32x4)0, a10 = (i32x4)0, a01 = (i32x4)0, a00 = (i32x4)0;
        const char* arow1 = A1 + (size_t)(bt * 16 + lm) * DRES;
        const char* arow0 = A0 + (size_t)(bt * 16 + lm) * DRES;
#pragma unroll 4
        for (int c = 0; c < 32; ++c) {
            int kb = c * 64 + lg * 16;
            i32x4 ah1 = *(const i32x4*)(arow1 + kb);
            i32x4 ah0 = *(const i32x4*)(arow0 + kb);
            i32x4 bw1 = *(const i32x4*)(lw1 + (kb ^ swz));
            i32x4 bw0 = *(const i32x4*)(lw0 + (kb ^ swz));
            a11 = __builtin_amdgcn_mfma_i32_16x16x64_i8(ah1, bw1, a11, 0, 0, 0);
            a10 = __builtin_amdgcn_mfma_i32_16x16x64_i8(ah1, bw0, a10, 0, 0, 0);
            a01 = __builtin_amdgcn_mfma_i32_16x16x64_i8(ah0, bw1, a01, 0, 0, 0);
            a00 = __builtin_amdgcn_mfma_i32_16x16x64_i8(ah0, bw0, a00, 0, 0, 0);
        }
        {
            char* O1 = hq1 + (size_t)(m & 1) * SLQ;
            char* O0 = hq0 + (size_t)(m & 1) * SLQ;
            int gr = gr0 + rloc;
#pragma unroll
            for (int j = 0; j < 4; ++j) {
                float pf = 65536.f * (float)a11[j] + 256.f * (float)(a10[j] + a01[j])
                         + (float)a00[j];
                float pre = pf * 0x1p-30f + us[j];
                float h = tanhf(pre);
                int b = bt * 16 + lg * 4 + j;
                st_hi[(size_t)m * SL + (size_t)b * DRES + gr] = f2bf(h);
                int q = (int)rintf(h * 16384.f);
                int d1 = (q + 128) >> 8;
                O1[(size_t)b * DRES + gr] = (char)d1;
                O0[(size_t)b * DRES + gr] = (char)(q - (d1 << 8));
            }
        }
        if (m < T_ - 1) {
            __syncthreads();          // all waves' stores issued
            if (tid == 0) {
                __threadfence();      // release: writeback toward coherence point
                unsigned prev = __hip_atomic_fetch_add(cnt, 1u, __ATOMIC_ACQ_REL,
                                                       __HIP_MEMORY_SCOPE_AGENT);
                if (prev == (unsigned)(NWG - 1)) {
                    __hip_atomic_store(cnt, 0u, __ATOMIC_RELAXED, __HIP_MEMORY_SCOPE_AGENT);
                    __hip_atomic_store(gen, (unsigned)m, __ATOMIC_RELEASE,
                                       __HIP_MEMORY_SCOPE_AGENT);
                } else {
                    while (__hip_atomic_load(gen, __ATOMIC_ACQUIRE,
                                             __HIP_MEMORY_SCOPE_AGENT) < (unsigned)m)
                        __builtin_amdgcn_s_sleep(8);
                }
                __threadfence();      // acquire: invalidate stale caches
            }
            __syncthreads();
        }
    }
}

// ---------------- readout: out[b][t][o] = states[t][b][:] . W_out[o][:] + b_out ----------------
__global__ __launch_bounds__(256) void readout_kern(
    const unsigned short* __restrict__ st_hi,
    const unsigned short* __restrict__ Wout_hi,
    const float* __restrict__ b_out, float* __restrict__ out) {
    const int n0 = blockIdx.x * 128;
    const int row0 = blockIdx.y * 64;
    const int tid = threadIdx.x;
    const int w = tid >> 6, l = tid & 63;
    const int lm = l & 15, lg = l >> 4;

    __shared__ __align__(16) unsigned short Bs[128][72];

    f32x4 acc[8];
#pragma unroll
    for (int nt = 0; nt < 8; ++nt) acc[nt] = (f32x4)0.f;

    const int row = row0 + w * 16 + lm;
    const long abase = (long)row * DRES;

    for (int s = 0; s < 32; ++s) {
#pragma unroll
        for (int q = 0; q < 4; ++q) {
            int idx = q * 256 + tid;
            int r_ = idx >> 3, k8 = idx & 7;
            *(short8*)&Bs[r_][k8 * 8] =
                *(const short8*)(Wout_hi + (long)(n0 + r_) * DRES + s * 64 + k8 * 8);
        }
        __syncthreads();
#pragma unroll
        for (int ki = 0; ki < 2; ++ki) {
            short8 a = *(const short8*)&st_hi[abase + s * 64 + ki * 32 + lg * 8];
#pragma unroll
            for (int nt = 0; nt < 8; ++nt) {
                short8 bf = *(const short8*)&Bs[nt * 16 + lm][ki * 32 + lg * 8];
                acc[nt] = __builtin_amdgcn_mfma_f32_16x16x32_bf16(a, bf, acc[nt], 0, 0, 0);
            }
        }
        __syncthreads();
    }
#pragma unroll
    for (int nt = 0; nt < 8; ++nt) {
        int o = n0 + nt * 16 + lm;
        float bias = b_out[o];
#pragma unroll
        for (int j = 0; j < 4; ++j) {
            int rr = row0 + w * 16 + lg * 4 + j;
            int t = rr >> 6, bb = rr & 63;
            out[((long)bb * T_ + t) * DOUT + o] = acc[nt][j] + bias;
        }
    }
}

extern "C" void kernel_launch(void* const* d_in, const int* in_sizes, int n_in,
                              void* d_out, int out_size, void* d_ws, size_t ws_size,
                              hipStream_t stream) {
    const float* x_res_init = (const float*)d_in[0];
    const float* x_in       = (const float*)d_in[1];
    const float* W_in       = (const float*)d_in[2];
    const float* b_in       = (const float*)d_in[3];
    const float* W_res      = (const float*)d_in[4];
    const float* W_out      = (const float*)d_in[5];
    const float* b_out      = (const float*)d_in[6];
    float* out = (float*)d_out;

    char* p = (char*)d_ws;
    auto alloc = [&](size_t bytes) -> char* {
        char* r = p;
        p += (bytes + 255) & ~(size_t)255;
        return r;
    };
    const size_t SL = (size_t)B_ * DRES;
    unsigned short* st_hi   = (unsigned short*)alloc((size_t)T_ * SL * 2);
    unsigned short* st_lo   = (unsigned short*)alloc((size_t)T_ * SL * 2);
    char*           wq1     = alloc((size_t)DRES * DRES);
    char*           wq0     = alloc((size_t)DRES * DRES);
    char*           hq1     = alloc(2 * (size_t)SLQ);
    char*           hq0     = alloc(2 * (size_t)SLQ);
    unsigned short* Win_hi  = (unsigned short*)alloc((size_t)DRES * DIN * 2);
    unsigned short* Win_lo  = (unsigned short*)alloc((size_t)DRES * DIN * 2);
    unsigned short* Wout_hi = (unsigned short*)alloc((size_t)DOUT * DRES * 2);
    unsigned short* Wout_lo = (unsigned short*)alloc((size_t)DOUT * DRES * 2);
    unsigned short* x_hi    = (unsigned short*)alloc((size_t)B_ * T_ * DIN * 2);
    unsigned short* x_lo    = (unsigned short*)alloc((size_t)B_ * T_ * DIN * 2);
    unsigned*       bar     = (unsigned*)alloc(256);

    hipMemsetAsync(bar, 0, 256, stream);

    auto launch_split = [&](const float* src, unsigned short* hi, unsigned short* lo, size_t n) {
        int n4 = (int)(n / 4);
        int blocks = (n4 + 255) / 256;
        if (blocks > 2048) blocks = 2048;
        split4_kern<<<blocks, 256, 0, stream>>>((const float4*)src, (ushort4*)hi, (ushort4*)lo, n4);
    };
    launch_split(W_in,  Win_hi,  Win_lo,  (size_t)DRES * DIN);
    launch_split(W_out, Wout_hi, Wout_lo, (size_t)DOUT * DRES);
    launch_split(x_in,  x_hi,    x_lo,    (size_t)B_ * T_ * DIN);
    launch_split(x_res_init, st_hi, st_lo, SL);   // states[0] (bf16, for readout)

    // quantize W_res (scale 2^16) and h_0 (scale 2^14) into digit planes
    quant_kern<<<2048, 256, 0, stream>>>(W_res, 65536.f, wq1, wq0, DRES * DRES);
    quant_kern<<<512, 256, 0, stream>>>(x_res_init, 16384.f, hq1, hq0, B_ * DRES);

    // u into states[1..255]
    u_gemm<<<dim3(32, T_ - 1), 256, 0, stream>>>(x_hi, x_lo, Win_hi, Win_lo, b_in, st_hi, st_lo);

    // persistent recurrence (cooperative): 64 WGs x 512 threads, 128 KiB LDS
    const size_t shmem = 131072;
    hipFuncSetAttribute(reinterpret_cast<const void*>(recur_persist),
                        hipFuncAttributeMaxDynamicSharedMemorySize, (int)shmem);
    void* kargs[] = { (void*)&wq1, (void*)&wq0, (void*)&hq1, (void*)&hq0,
                      (void*)&st_hi, (void*)&st_lo, (void*)&bar };
    hipLaunchCooperativeKernel((const void*)recur_persist, dim3(NWG), dim3(512),
                               kargs, (unsigned int)shmem, stream);

    // readout
    readout_kern<<<dim3(4, 256), 256, 0, stream>>>(st_hi, Wout_hi, b_out, out);
}

// Round 5
// 4873.734 us; speedup vs baseline: 1.5736x; 1.1658x over previous
//
#include <hip/hip_runtime.h>
#include <hip/hip_bf16.h>

// ESN: h_m = tanh(W_res h_{m-1} + W_in x_{m-1} + b_in), readout on all states.
// Recurrence: ONE persistent cooperative kernel, 64 WGs x 512 threads.
// W_res as two signed-i8 digit planes (scale 2^16) stationary in LDS (128KiB,
// swizzled); h as two i8 digit planes (scale 2^14) double-buffered in global,
// accessed ONLY via sc0 sc1 (coherence-point) loads/stores -> no L2 cache
// maintenance walks. Relaxed monotonic-counter grid barrier. Software-
// pipelined A loads (4 windows, counted vmcnt waits).

#define B_   64
#define T_   256
#define DIN  512
#define DRES 2048
#define DOUT 512
#define NWG  64
#define SLQ  131072   // one h digit-plane slice: 64*2048 bytes

typedef __attribute__((ext_vector_type(8))) short short8;
typedef __attribute__((ext_vector_type(4))) float f32x4;
typedef __attribute__((ext_vector_type(4))) int i32x4;

__device__ __forceinline__ unsigned short f2bf(float x) {
    unsigned int u = __float_as_uint(x);
    unsigned int r = u + 0x7fffu + ((u >> 16) & 1u);
    return (unsigned short)(r >> 16);
}
__device__ __forceinline__ float bf2f(unsigned short h) {
    return __uint_as_float(((unsigned int)h) << 16);
}

// ---------------- split f32 -> bf16 hi/lo ----------------
__global__ void split4_kern(const float4* __restrict__ src,
                            ushort4* __restrict__ hi, ushort4* __restrict__ lo, int n4) {
    int i = blockIdx.x * blockDim.x + threadIdx.x;
    int st = gridDim.x * blockDim.x;
    for (; i < n4; i += st) {
        float4 v = src[i];
        ushort4 h, l;
        h.x = f2bf(v.x); l.x = f2bf(v.x - bf2f(h.x));
        h.y = f2bf(v.y); l.y = f2bf(v.y - bf2f(h.y));
        h.z = f2bf(v.z); l.z = f2bf(v.z - bf2f(h.z));
        h.w = f2bf(v.w); l.w = f2bf(v.w - bf2f(h.w));
        hi[i] = h; lo[i] = l;
    }
}

// ---------------- quantize f32 -> two signed-i8 digit planes ----------------
__global__ void quant_kern(const float* __restrict__ src, float scale,
                           char* __restrict__ d1, char* __restrict__ d0, int n) {
    int i = blockIdx.x * blockDim.x + threadIdx.x;
    int st = gridDim.x * blockDim.x;
    for (; i < n; i += st) {
        int q = (int)rintf(src[i] * scale);
        q = min(max(q, -32640), 32639);
        int h1 = (q + 128) >> 8;
        d1[i] = (char)h1;
        d0[i] = (char)(q - (h1 << 8));
    }
}

// ---------------- u GEMM: states[m] = x_in[:,m-1,:] @ W_in^T + b_in ----------------
__global__ __launch_bounds__(256) void u_gemm(
    const unsigned short* __restrict__ x_hi, const unsigned short* __restrict__ x_lo,
    const unsigned short* __restrict__ Win_hi, const unsigned short* __restrict__ Win_lo,
    const float* __restrict__ b_in,
    unsigned short* __restrict__ st_hi, unsigned short* __restrict__ st_lo) {
    const int t = blockIdx.y;            // 0..254 -> m = t+1
    const int r0 = blockIdx.x * 64;
    const int tid = threadIdx.x;
    const int w = tid >> 6, l = tid & 63;
    const int lm = l & 15, lg = l >> 4;

    __shared__ __align__(16) unsigned short Bs[2][64][72];

    f32x4 acc[4][3];
#pragma unroll
    for (int nt = 0; nt < 4; ++nt)
#pragma unroll
        for (int q = 0; q < 3; ++q) acc[nt][q] = (f32x4)0.0f;

    const int ab = w * 16 + lm;
    const long xbase = ((long)ab * T_ + t) * DIN;

    for (int s = 0; s < 8; ++s) {
#pragma unroll
        for (int q = 0; q < 4; ++q) {
            int idx = q * 256 + tid;
            int mt = idx >> 9;
            int rem = idx & 511;
            int row = rem >> 3, k8 = rem & 7;
            const unsigned short* sp =
                (mt ? Win_lo : Win_hi) + (long)(r0 + row) * DIN + s * 64 + k8 * 8;
            *(short8*)&Bs[mt][row][k8 * 8] = *(const short8*)sp;
        }
        __syncthreads();
#pragma unroll
        for (int ki = 0; ki < 2; ++ki) {
            int k = s * 64 + ki * 32 + lg * 8;
            short8 ahi = *(const short8*)&x_hi[xbase + k];
            short8 alo = *(const short8*)&x_lo[xbase + k];
#pragma unroll
            for (int nt = 0; nt < 4; ++nt) {
                short8 bhi = *(const short8*)&Bs[0][nt * 16 + lm][ki * 32 + lg * 8];
                short8 blo = *(const short8*)&Bs[1][nt * 16 + lm][ki * 32 + lg * 8];
                acc[nt][0] = __builtin_amdgcn_mfma_f32_16x16x32_bf16(ahi, bhi, acc[nt][0], 0, 0, 0);
                acc[nt][1] = __builtin_amdgcn_mfma_f32_16x16x32_bf16(ahi, blo, acc[nt][1], 0, 0, 0);
                acc[nt][2] = __builtin_amdgcn_mfma_f32_16x16x32_bf16(alo, bhi, acc[nt][2], 0, 0, 0);
            }
        }
        __syncthreads();
    }
    const int m = t + 1;
#pragma unroll
    for (int nt = 0; nt < 4; ++nt) {
        f32x4 s4 = acc[nt][0] + acc[nt][1] + acc[nt][2];
        int r = r0 + nt * 16 + lm;
        float bias = b_in[r];
#pragma unroll
        for (int j = 0; j < 4; ++j) {
            int bb = w * 16 + lg * 4 + j;
            float v = s4[j] + bias;
            unsigned short h = f2bf(v);
            long o = ((long)m * B_ + bb) * DRES + r;
            st_hi[o] = h;
            st_lo[o] = f2bf(v - bf2f(h));
        }
    }
}

// ---------------- persistent recurrence ----------------
// 64 WGs x 512 threads (8 waves). WG owns rows gr0..gr0+31, full K=2048.
// W digit planes in LDS (128 KiB, swizzled). Wave w: rt = w>>2 (row half),
// bt = w&3 (batch quarter); each wave computes a full-K 16x16 tile alone.
#define MFI8(a, b, c) __builtin_amdgcn_mfma_i32_16x16x64_i8(a, b, c, 0, 0, 0)

__global__ __launch_bounds__(512, 2) void recur_persist(
    const char* __restrict__ wq1, const char* __restrict__ wq0,
    char* __restrict__ hq1, char* __restrict__ hq0,
    unsigned short* __restrict__ st_hi, const unsigned short* __restrict__ st_lo,
    unsigned* __restrict__ bar) {
    extern __shared__ char smem[];               // [0,64K): W1, [64K,128K): W0
    const int gr0 = blockIdx.x * 32;
    const int tid = threadIdx.x;
    const int w = tid >> 6, l = tid & 63;
    const int lm = l & 15, lg = l >> 4;
    const int rt = w >> 2, bt = w & 3;
    const int rloc = rt * 16 + lm;
    const int swz = (rloc & 7) << 4;
    const int lgo = lg * 16;
    const size_t SL = (size_t)B_ * DRES;

    // stage W digit planes once (swizzled 16B chunks; ordinary cached loads)
    for (int c = tid; c < 8192; c += 512) {
        int mat = c >> 12;
        int rem = c & 4095;
        int row = rem >> 7, k16 = rem & 127;
        const char* src = (mat ? wq0 : wq1) + (size_t)(gr0 + row) * DRES + k16 * 16;
        int dst = mat * 65536 + row * 2048 + ((k16 * 16) ^ ((row & 7) << 4));
        *(i32x4*)(smem + dst) = *(const i32x4*)src;
    }
    __syncthreads();

    const char* lw1 = smem + rloc * 2048;
    const char* lw0 = smem + 65536 + rloc * 2048;

#define ISSUE_W(B1, B0, c0)                                                     \
    do {                                                                        \
        _Pragma("unroll")                                                       \
        for (int i = 0; i < 8; ++i) {                                           \
            asm volatile("global_load_dwordx4 %0, %1, off sc0 sc1"              \
                         : "=v"(B1[i]) : "v"(arow1 + (c0 + i) * 64 + lgo));     \
            asm volatile("global_load_dwordx4 %0, %1, off sc0 sc1"              \
                         : "=v"(B0[i]) : "v"(arow0 + (c0 + i) * 64 + lgo));     \
        }                                                                       \
    } while (0)

#define COMP_W(B1, B0, c0)                                                      \
    do {                                                                        \
        _Pragma("unroll")                                                       \
        for (int i = 0; i < 8; ++i) {                                           \
            int kb = (c0 + i) * 64 + lgo;                                       \
            i32x4 bw1 = *(const i32x4*)(lw1 + (kb ^ swz));                      \
            i32x4 bw0 = *(const i32x4*)(lw0 + (kb ^ swz));                      \
            a11 = MFI8(B1[i], bw1, a11);                                        \
            a10 = MFI8(B1[i], bw0, a10);                                        \
            a01 = MFI8(B0[i], bw1, a01);                                        \
            a00 = MFI8(B0[i], bw0, a00);                                        \
        }                                                                       \
    } while (0)

#define VMWAIT16() do { asm volatile("s_waitcnt vmcnt(16)" ::: "memory"); \
                        __builtin_amdgcn_sched_barrier(0); } while (0)
#define VMWAIT0()  do { asm volatile("s_waitcnt vmcnt(0)" ::: "memory");  \
                        __builtin_amdgcn_sched_barrier(0); } while (0)

    for (int m = 1; m < T_; ++m) {
        const char* A1 = hq1 + (size_t)((m - 1) & 1) * SLQ;
        const char* A0 = hq0 + (size_t)((m - 1) & 1) * SLQ;
        const char* arow1 = A1 + (size_t)(bt * 16 + lm) * DRES;
        const char* arow0 = A0 + (size_t)(bt * 16 + lm) * DRES;

        // u stash (ordinary cached loads; raw ushorts, converted in epilogue)
        unsigned short uh[4], ul[4];
        {
            const unsigned short* su = st_hi + (size_t)m * SL + gr0 + rloc;
            const unsigned short* sv = st_lo + (size_t)m * SL + gr0 + rloc;
#pragma unroll
            for (int j = 0; j < 4; ++j) {
                size_t o = (size_t)(bt * 16 + lg * 4 + j) * DRES;
                uh[j] = su[o];
                ul[j] = sv[o];
            }
        }

        i32x4 a11 = (i32x4)0, a10 = (i32x4)0, a01 = (i32x4)0, a00 = (i32x4)0;
        i32x4 P1[8], P0[8], Q1[8], Q0[8];

        ISSUE_W(P1, P0, 0);
        ISSUE_W(Q1, Q0, 8);
        VMWAIT16();
        COMP_W(P1, P0, 0);
        ISSUE_W(P1, P0, 16);
        VMWAIT16();
        COMP_W(Q1, Q0, 8);
        ISSUE_W(Q1, Q0, 24);
        VMWAIT16();
        COMP_W(P1, P0, 16);
        VMWAIT0();
        COMP_W(Q1, Q0, 24);

        // epilogue: pre-activation -> tanh -> bf16 state + i8 digit planes
        {
            int gr = gr0 + rloc;
            unsigned short* sh = st_hi + (size_t)m * SL;
            char* O1 = hq1 + (size_t)(m & 1) * SLQ;
            char* O0 = hq0 + (size_t)(m & 1) * SLQ;
#pragma unroll
            for (int j = 0; j < 4; ++j) {
                float pf = 65536.f * (float)a11[j] + 256.f * (float)(a10[j] + a01[j])
                         + (float)a00[j];
                float pre = pf * 0x1p-30f + bf2f(uh[j]) + bf2f(ul[j]);
                float h = tanhf(pre);
                int b = bt * 16 + lg * 4 + j;
                sh[(size_t)b * DRES + gr] = f2bf(h);
                if (m < T_ - 1) {
                    int q = (int)rintf(h * 16384.f);
                    int d1 = (q + 128) >> 8;
                    int d0 = q - (d1 << 8);
                    asm volatile("global_store_byte %0, %1, off sc0 sc1"
                                 :: "v"(O1 + (size_t)b * DRES + gr), "v"(d1) : "memory");
                    asm volatile("global_store_byte %0, %1, off sc0 sc1"
                                 :: "v"(O0 + (size_t)b * DRES + gr), "v"(d0) : "memory");
                }
            }
        }

        if (m < T_ - 1) {
            // release: every wave drains its (untracked) asm stores, then WG barrier
            asm volatile("s_waitcnt vmcnt(0)" ::: "memory");
            __syncthreads();
            if (tid == 0) {
                __hip_atomic_fetch_add(bar, 1u, __ATOMIC_RELAXED, __HIP_MEMORY_SCOPE_AGENT);
                const unsigned target = (unsigned)m * NWG;
                while (__hip_atomic_load(bar, __ATOMIC_RELAXED, __HIP_MEMORY_SCOPE_AGENT)
                       < target)
                    __builtin_amdgcn_s_sleep(8);
            }
            __syncthreads();
        }
    }
#undef ISSUE_W
#undef COMP_W
#undef VMWAIT16
#undef VMWAIT0
}

// ---------------- readout: out[b][t][o] = states[t][b][:] . W_out[o][:] + b_out ----------------
__global__ __launch_bounds__(256) void readout_kern(
    const unsigned short* __restrict__ st_hi,
    const unsigned short* __restrict__ Wout_hi,
    const float* __restrict__ b_out, float* __restrict__ out) {
    const int n0 = blockIdx.x * 128;
    const int row0 = blockIdx.y * 64;
    const int tid = threadIdx.x;
    const int w = tid >> 6, l = tid & 63;
    const int lm = l & 15, lg = l >> 4;

    __shared__ __align__(16) unsigned short Bs[128][72];

    f32x4 acc[8];
#pragma unroll
    for (int nt = 0; nt < 8; ++nt) acc[nt] = (f32x4)0.f;

    const int row = row0 + w * 16 + lm;
    const long abase = (long)row * DRES;

    for (int s = 0; s < 32; ++s) {
#pragma unroll
        for (int q = 0; q < 4; ++q) {
            int idx = q * 256 + tid;
            int r_ = idx >> 3, k8 = idx & 7;
            *(short8*)&Bs[r_][k8 * 8] =
                *(const short8*)(Wout_hi + (long)(n0 + r_) * DRES + s * 64 + k8 * 8);
        }
        __syncthreads();
#pragma unroll
        for (int ki = 0; ki < 2; ++ki) {
            short8 a = *(const short8*)&st_hi[abase + s * 64 + ki * 32 + lg * 8];
#pragma unroll
            for (int nt = 0; nt < 8; ++nt) {
                short8 bf = *(const short8*)&Bs[nt * 16 + lm][ki * 32 + lg * 8];
                acc[nt] = __builtin_amdgcn_mfma_f32_16x16x32_bf16(a, bf, acc[nt], 0, 0, 0);
            }
        }
        __syncthreads();
    }
#pragma unroll
    for (int nt = 0; nt < 8; ++nt) {
        int o = n0 + nt * 16 + lm;
        float bias = b_out[o];
#pragma unroll
        for (int j = 0; j < 4; ++j) {
            int rr = row0 + w * 16 + lg * 4 + j;
            int t = rr >> 6, bb = rr & 63;
            out[((long)bb * T_ + t) * DOUT + o] = acc[nt][j] + bias;
        }
    }
}

extern "C" void kernel_launch(void* const* d_in, const int* in_sizes, int n_in,
                              void* d_out, int out_size, void* d_ws, size_t ws_size,
                              hipStream_t stream) {
    const float* x_res_init = (const float*)d_in[0];
    const float* x_in       = (const float*)d_in[1];
    const float* W_in       = (const float*)d_in[2];
    const float* b_in       = (const float*)d_in[3];
    const float* W_res      = (const float*)d_in[4];
    const float* W_out      = (const float*)d_in[5];
    const float* b_out      = (const float*)d_in[6];
    float* out = (float*)d_out;

    char* p = (char*)d_ws;
    auto alloc = [&](size_t bytes) -> char* {
        char* r = p;
        p += (bytes + 255) & ~(size_t)255;
        return r;
    };
    const size_t SL = (size_t)B_ * DRES;
    unsigned short* st_hi   = (unsigned short*)alloc((size_t)T_ * SL * 2);
    unsigned short* st_lo   = (unsigned short*)alloc((size_t)T_ * SL * 2);
    char*           wq1     = alloc((size_t)DRES * DRES);
    char*           wq0     = alloc((size_t)DRES * DRES);
    char*           hq1     = alloc(2 * (size_t)SLQ);
    char*           hq0     = alloc(2 * (size_t)SLQ);
    unsigned short* Win_hi  = (unsigned short*)alloc((size_t)DRES * DIN * 2);
    unsigned short* Win_lo  = (unsigned short*)alloc((size_t)DRES * DIN * 2);
    unsigned short* Wout_hi = (unsigned short*)alloc((size_t)DOUT * DRES * 2);
    unsigned short* Wout_lo = (unsigned short*)alloc((size_t)DOUT * DRES * 2);
    unsigned short* x_hi    = (unsigned short*)alloc((size_t)B_ * T_ * DIN * 2);
    unsigned short* x_lo    = (unsigned short*)alloc((size_t)B_ * T_ * DIN * 2);
    unsigned*       bar     = (unsigned*)alloc(256);

    hipMemsetAsync(bar, 0, 256, stream);

    auto launch_split = [&](const float* src, unsigned short* hi, unsigned short* lo, size_t n) {
        int n4 = (int)(n / 4);
        int blocks = (n4 + 255) / 256;
        if (blocks > 2048) blocks = 2048;
        split4_kern<<<blocks, 256, 0, stream>>>((const float4*)src, (ushort4*)hi, (ushort4*)lo, n4);
    };
    launch_split(W_in,  Win_hi,  Win_lo,  (size_t)DRES * DIN);
    launch_split(W_out, Wout_hi, Wout_lo, (size_t)DOUT * DRES);
    launch_split(x_in,  x_hi,    x_lo,    (size_t)B_ * T_ * DIN);
    launch_split(x_res_init, st_hi, st_lo, SL);   // states[0] (bf16, for readout)

    // quantize W_res (scale 2^16) and h_0 (scale 2^14) into digit planes
    quant_kern<<<2048, 256, 0, stream>>>(W_res, 65536.f, wq1, wq0, DRES * DRES);
    quant_kern<<<512, 256, 0, stream>>>(x_res_init, 16384.f, hq1, hq0, B_ * DRES);

    // u into states[1..255]
    u_gemm<<<dim3(32, T_ - 1), 256, 0, stream>>>(x_hi, x_lo, Win_hi, Win_lo, b_in, st_hi, st_lo);

    // persistent recurrence (cooperative): 64 WGs x 512 threads, 128 KiB LDS
    const size_t shmem = 131072;
    hipFuncSetAttribute(reinterpret_cast<const void*>(recur_persist),
                        hipFuncAttributeMaxDynamicSharedMemorySize, (int)shmem);
    void* kargs[] = { (void*)&wq1, (void*)&wq0, (void*)&hq1, (void*)&hq0,
                      (void*)&st_hi, (void*)&st_lo, (void*)&bar };
    hipLaunchCooperativeKernel((const void*)recur_persist, dim3(NWG), dim3(512),
                               kargs, (unsigned int)shmem, stream);

    // readout
    readout_kern<<<dim3(4, 256), 256, 0, stream>>>(st_hi, Wout_hi, b_out, out);
}